// Round 1
// baseline (327.352 us; speedup 1.0000x reference)
//
#include <hip/hip_runtime.h>

// Problem constants (from reference):
// patches: [N=128, C=4, P=32, P, P] fp32
// vol:     [B=2,  C=4, H=128, H, H] fp32
// centers: [N, 3] int32 ; lo = center - P/2 ; b = n / (N/B) = n/64
// out = vol*0.5 ; out[b,c,lo0+i,lo1+j,lo2+k] += 0.5*patch[n,c,i,j,k] (scatter-add, overlaps accumulate)

#define PW 0.5f

__global__ void scale_vol_kernel(const float4* __restrict__ vol,
                                 float4* __restrict__ out, int n4) {
    int i = blockIdx.x * blockDim.x + threadIdx.x;
    int stride = gridDim.x * blockDim.x;
    for (; i < n4; i += stride) {
        float4 v = vol[i];
        v.x *= (1.0f - PW);
        v.y *= (1.0f - PW);
        v.z *= (1.0f - PW);
        v.w *= (1.0f - PW);
        out[i] = v;
    }
}

// One thread handles 4 consecutive d-voxels of one patch -> float4 load of
// patch data (coalesced), 4 atomicAdds to consecutive fp32 addresses in out
// (coalesced RMW along vol's contiguous innermost dim).
__global__ void scatter_patches_kernel(const float4* __restrict__ patches4,
                                       const int* __restrict__ centers,
                                       float* __restrict__ out) {
    int t = blockIdx.x * blockDim.x + threadIdx.x;  // [0, N*C*P*P*P/4) = [0, 4194304)
    // decompose: t = ((((n*4 + c)*32 + h)*32 + w)*8 + d4)
    int d4 = t & 7;          // which float4 along d
    int w  = (t >> 3) & 31;
    int h  = (t >> 8) & 31;
    int c  = (t >> 13) & 3;
    int n  = t >> 15;
    int b  = n >> 6;         // n / 64 patches per batch

    int lo0 = centers[n * 3 + 0] - 16;
    int lo1 = centers[n * 3 + 1] - 16;
    int lo2 = centers[n * 3 + 2] - 16;

    float4 p = patches4[t];

    // out index: ((b*4 + c)*128 + (lo0+h))*128*128 + (lo1+w)*128 + (lo2 + d4*4)
    int idx = (((b * 4 + c) * 128 + (lo0 + h)) * 128 + (lo1 + w)) * 128 + lo2 + d4 * 4;
    float* o = out + idx;
    atomicAdd(o + 0, p.x * PW);
    atomicAdd(o + 1, p.y * PW);
    atomicAdd(o + 2, p.z * PW);
    atomicAdd(o + 3, p.w * PW);
}

extern "C" void kernel_launch(void* const* d_in, const int* in_sizes, int n_in,
                              void* d_out, int out_size, void* d_ws, size_t ws_size,
                              hipStream_t stream) {
    const float* patches = (const float*)d_in[0];   // 128*4*32^3 = 16777216 floats
    const float* vol     = (const float*)d_in[1];   // 2*4*128^3  = 16777216 floats
    const int*   centers = (const int*)d_in[2];     // 128*3 int32
    float* out = (float*)d_out;                     // 16777216 floats

    // Kernel 1: out = vol * (1 - PW), float4 vectorized.
    int n4 = out_size / 4;                          // 4194304 float4s
    scale_vol_kernel<<<2048, 256, 0, stream>>>((const float4*)vol, (float4*)out, n4);

    // Kernel 2: scatter-add patches (overlap-safe via atomics).
    int total4 = (128 * 4 * 32 * 32 * 32) / 4;      // 4194304 threads
    scatter_patches_kernel<<<total4 / 256, 256, 0, stream>>>(
        (const float4*)patches, centers, out);
}

// Round 3
// 56.324 us; speedup vs baseline: 5.8120x; 5.8120x over previous
//
#include <hip/hip_runtime.h>

// patches: [N=128, C=4, P=32, P, P] fp32
// vol:     [B=2,  C=4, H=128, H, H] fp32
// centers: [N, 3] int32 ; lo = center - P/2 ; patch n belongs to batch b = n/64
// out = vol*(1-PW) + PW * scatter(patches)  -- computed as a GATHER:
// every patch voxel lands on exactly one output voxel, so per output voxel we
// sum the (expected ~1) patches whose 32^3 box covers it. No atomics.

#define PW 0.5f
constexpr int B = 2, C = 4, H = 128, NPATCH = 128, P = 32;
constexpr int NPB = NPATCH / B;          // 64 patches per batch
constexpr int CH_STRIDE = H * H * H;     // fp32 elems per channel of vol
constexpr int PCH = P * P * P;           // fp32 elems per channel of a patch

__global__ __launch_bounds__(256) void patch_gather_kernel(
        const float* __restrict__ patches,
        const int*   __restrict__ centers,
        const float4* __restrict__ vol4,
        float4* __restrict__ out4) {
    __shared__ int slo[NPB][3];

    // 4096 blocks: 2048 per batch
    int b = blockIdx.x >> 11;
    int tid = threadIdx.x;

    // stage this batch's patch lower bounds into LDS
    if (tid < NPB * 3) {
        int pn = tid / 3, ax = tid % 3;
        slo[pn][ax] = centers[(b * NPB + pn) * 3 + ax] - P / 2;
    }
    __syncthreads();

    // thread -> (h, w, d0): 2048 blocks * 256 threads = 524288 = 128*128*32 per batch
    int t  = (blockIdx.x & 2047) * 256 + tid;
    int d0 = (t & 31) * 4;          // first of 4 consecutive d voxels
    int w  = (t >> 5) & 127;
    int h  = t >> 12;

    float acc[C][4] = {};

    for (int pn = 0; pn < NPB; ++pn) {
        int lo0 = slo[pn][0];
        int lo1 = slo[pn][1];
        int lo2 = slo[pn][2];
        unsigned hi = (unsigned)(h - lo0);
        unsigned wi = (unsigned)(w - lo1);
        if (hi < P && wi < P) {
            int k0 = d0 - lo2;                   // patch-k of element e=0
            if (k0 > -4 && k0 < P) {             // any of the 4 d's inside
                const float* pb = patches
                    + ((size_t)(b * NPB + pn) * C) * PCH + hi * (P * P) + wi * P;
                #pragma unroll
                for (int e = 0; e < 4; ++e) {
                    int k = k0 + e;
                    if ((unsigned)k < P) {
                        #pragma unroll
                        for (int c = 0; c < C; ++c)
                            acc[c][e] += pb[c * PCH + k];
                    }
                }
            }
        }
    }

    // fused epilogue: out = vol*(1-PW) + PW*acc ; float4 along d
    #pragma unroll
    for (int c = 0; c < C; ++c) {
        int idx4 = ((((b * C + c) * H + h) * H + w) * H + d0) >> 2;
        float4 v = vol4[idx4];
        float4 o;
        o.x = v.x * (1.0f - PW) + acc[c][0] * PW;
        o.y = v.y * (1.0f - PW) + acc[c][1] * PW;
        o.z = v.z * (1.0f - PW) + acc[c][2] * PW;
        o.w = v.w * (1.0f - PW) + acc[c][3] * PW;
        out4[idx4] = o;
    }
}

extern "C" void kernel_launch(void* const* d_in, const int* in_sizes, int n_in,
                              void* d_out, int out_size, void* d_ws, size_t ws_size,
                              hipStream_t stream) {
    const float* patches = (const float*)d_in[0];
    const float* vol     = (const float*)d_in[1];
    const int*   centers = (const int*)d_in[2];
    float* out = (float*)d_out;

    patch_gather_kernel<<<4096, 256, 0, stream>>>(
        patches, centers, (const float4*)vol, (float4*)out);
}

// Round 5
// 53.629 us; speedup vs baseline: 6.1040x; 1.0502x over previous
//
#include <hip/hip_runtime.h>

// patches: [N=128, C=4, P=32, P, P] fp32
// vol:     [B=2,  C=4, H=128, H, H] fp32
// centers: [N, 3] int32 ; lo = center - 16 ; patch n -> batch b = n/64
// out = vol*(1-PW) + PW * scatter(patches), computed as a gather (no atomics).
// Block footprint: h fixed, w in [w0,w0+7], d all 128 -> per-block patch
// filtering (wave 0, ballot-compacted) cuts the 64-iter loop to ~5 survivors.

#define PW 0.5f
constexpr int C = 4, H = 128, P = 32;
constexpr int NPB = 64;              // patches per batch
constexpr int PCH = P * P * P;       // 32768 floats per patch channel

__global__ __launch_bounds__(256) void patch_gather_kernel(
        const float* __restrict__ patches,
        const int*   __restrict__ centers,
        const float4* __restrict__ vol4,
        float4* __restrict__ out4) {
    __shared__ int s_list[NPB];
    __shared__ int s_n;

    int blk = blockIdx.x;
    int b   = blk >> 11;             // 2048 blocks per batch
    int blo = blk & 2047;
    int tid = threadIdx.x;

    int h  = blo >> 4;               // block-uniform h
    int w0 = (blo << 3) & 127;       // block covers w0..w0+7

    // wave 0: filter this batch's 64 patches against the block footprint
    if (tid < 64) {
        int pn  = tid;
        int lo0 = centers[(b * NPB + pn) * 3 + 0] - 16;
        int lo1 = centers[(b * NPB + pn) * 3 + 1] - 16;
        int lo2 = centers[(b * NPB + pn) * 3 + 2] - 16;
        bool hit = ((unsigned)(h - lo0) < P) &&
                   ((unsigned)(w0 - lo1 + 7) < (P + 7));   // w-range intersect
        unsigned long long m = __ballot(hit);
        if (hit) {
            int pos = __popcll(m & ((1ull << tid) - 1ull));
            s_list[pos] = (pn << 21) | (lo0 << 14) | (lo1 << 7) | lo2;
        }
        if (tid == 0) s_n = __popcll(m);
    }
    __syncthreads();

    int d0 = (tid & 31) * 4;         // 4 consecutive d voxels
    int w  = w0 + (tid >> 5);

    float acc[C][4] = {};
    int nh = s_n;                    // uniform trip count
    const float* pbatch = patches + (size_t)b * NPB * C * PCH;

    for (int i = 0; i < nh; ++i) {
        int e   = s_list[i];         // broadcast LDS read
        int pn  = e >> 21;
        int lo1 = (e >> 7) & 127;
        unsigned wi = (unsigned)(w - lo1);
        if (wi < P) {
            int lo0 = (e >> 14) & 127;
            int lo2 = e & 127;
            int hi  = h - lo0;       // in [0,32) by filter
            int k0  = d0 - lo2;
            if (k0 > -4 && k0 < P) {
                const float* pb = pbatch + (size_t)pn * C * PCH
                                + hi * (P * P) + wi * P;
                #pragma unroll
                for (int e4 = 0; e4 < 4; ++e4) {
                    int k = k0 + e4;
                    if ((unsigned)k < P) {
                        #pragma unroll
                        for (int c = 0; c < C; ++c)
                            acc[c][e4] += pb[c * PCH + k];
                    }
                }
            }
        }
    }

    // fused epilogue: out = vol*(1-PW) + PW*acc, float4 along d
    #pragma unroll
    for (int c = 0; c < C; ++c) {
        int idx4 = ((((b * C + c) * H + h) * H + w) * H + d0) >> 2;
        float4 v = vol4[idx4];
        float4 o;
        o.x = v.x * (1.0f - PW) + acc[c][0] * PW;
        o.y = v.y * (1.0f - PW) + acc[c][1] * PW;
        o.z = v.z * (1.0f - PW) + acc[c][2] * PW;
        o.w = v.w * (1.0f - PW) + acc[c][3] * PW;
        out4[idx4] = o;
    }
}

extern "C" void kernel_launch(void* const* d_in, const int* in_sizes, int n_in,
                              void* d_out, int out_size, void* d_ws, size_t ws_size,
                              hipStream_t stream) {
    const float* patches = (const float*)d_in[0];
    const float* vol     = (const float*)d_in[1];
    const int*   centers = (const int*)d_in[2];
    float* out = (float*)d_out;

    patch_gather_kernel<<<4096, 256, 0, stream>>>(
        patches, centers, (const float4*)vol, (float4*)out);
}